// Round 1
// 207.946 us; speedup vs baseline: 1.0079x; 1.0079x over previous
//
#include <hip/hip_runtime.h>
#include <math.h>

#define EPS32 1.1920928955078125e-07f
#define NSP 32768          // 2*128*128 spatial positions
#define HB 128             // heatmap blocks
#define PB 4096            // pool blocks (64ch * 2d * 128h * 64 float4-pairs / 256 thr)

// Clang native vector types — required for __builtin_nontemporal_* (HIP_vector_type structs are rejected)
typedef float v4f __attribute__((ext_vector_type(4)));
typedef float v2f __attribute__((ext_vector_type(2)));

// ---------------- ws layout (float units) ----------------
// 0     : partial[128]
// 1024  : hmv[32768]
// 65536 : pooled[64*32768]

__device__ __forceinline__ float gauss_radius(float h, float w) {
#pragma clang fp contract(off)
    const float mo = 0.1f;
    float b1 = h + w;
    float c1 = w * h * (1.0f - mo) / (1.0f + mo);
    float r1 = (b1 + sqrtf(fmaxf(b1 * b1 - 4.0f * c1, 0.0f))) / 2.0f;
    float b2 = 2.0f * (h + w);
    float c2 = (1.0f - mo) * w * h;
    float r2 = (b2 + sqrtf(fmaxf(b2 * b2 - 16.0f * c2, 0.0f))) / 2.0f;
    float b3 = -2.0f * mo * (h + w);
    float c3 = (mo - 1.0f) * w * h;
    float r3 = (b3 + sqrtf(fmaxf(b3 * b3 - 16.0f * mo * c3, 0.0f))) / 2.0f;
    return fminf(fminf(r1, r2), r3);
}

// blocks [0,HB): heatmap (+ in-LDS box params + per-block partial sum)
// blocks [HB, HB+PB): 2x2x2 average pool of student with nontemporal float4 loads
__global__ void k_stage1(const float* __restrict__ boxes, int N,
                         const float* __restrict__ S,
                         float* __restrict__ P,
                         float* __restrict__ hmv,
                         float* __restrict__ partial) {
    int bx = blockIdx.x;
    int tid = threadIdx.x;

    if (bx < HB) {
        __shared__ int   s_cxi[128], s_cyi[128], s_czi[128], s_rx[128], s_rz[128];
        __shared__ float s_ix[128], s_iz[128];
        if (tid < N) {
#pragma clang fp contract(off)
            int b = tid;
            float x = boxes[b * 9 + 0];
            float y = boxes[b * 9 + 1];
            float z = boxes[b * 9 + 2];
            float wf = boxes[b * 9 + 3] / 0.1f / 8.0f;
            float lf = boxes[b * 9 + 4] / 0.1f / 8.0f;
            float hf = boxes[b * 9 + 5] / 0.2f / 8.0f;
            float r_xy = gauss_radius(lf, wf);
            float r_z  = fmaxf(gauss_radius(lf, hf), gauss_radius(wf, hf));
            int rx = max(2, (int)truncf(r_xy / 0.4f));
            int rz = max(2, (int)truncf(r_z / 1.0f));
            float cx = (x + 51.2f) / 0.4f;
            float cy = (y + 51.2f) / 0.4f;
            float cz = (z + 5.0f) / 1.0f;
            int cxi = (int)cx, cyi = (int)cy, czi = (int)cz;
            int valid = (wf > 0.0f) && (lf > 0.0f) &&
                        cxi >= 0 && cxi < 128 && cyi >= 0 && cyi < 128 &&
                        czi >= 0 && czi <= 1;
            float sx = (2.0f * (float)rx + 1.0f) / 6.0f;
            float sz = (2.0f * (float)rz + 1.0f) / 6.0f;
            s_cxi[b] = cxi;
            s_cyi[b] = cyi;
            s_czi[b] = czi;
            s_rx[b]  = valid ? rx : -1;   // rx=-1 makes window test always fail
            s_rz[b]  = rz;
            s_ix[b]  = 1.0f / (2.0f * sx * sx);
            s_iz[b]  = 1.0f / (2.0f * sz * sz);
        }
        __syncthreads();

        int i = bx * 256 + tid;
        int y = i & 127, x = (i >> 7) & 127, zc = i >> 14;
        float m = 0.0f;
        for (int b = 0; b < N; ++b) {
            int rx = s_rx[b];
            int dx = x - s_cxi[b];
            if (dx > rx || dx < -rx) continue;
            int dy = y - s_cyi[b];
            if (dy > rx || dy < -rx) continue;
            int rz = s_rz[b];
            int dz = zc - s_czi[b];
            if (dz > rz || dz < -rz) continue;
            float e = (float)(dx * dx + dy * dy) * s_ix[b]
                    + (float)(dz * dz) * s_iz[b];
            float g = expf(-e);
            if (g >= EPS32) m = fmaxf(m, g);
        }
        hmv[i] = m;
        __shared__ float sm[256];
        sm[tid] = m;
        __syncthreads();
        for (int s = 128; s > 0; s >>= 1) {
            if (tid < s) sm[tid] += sm[tid + s];
            __syncthreads();
        }
        if (tid == 0) partial[bx] = sm[0];
    } else {
        int j = (bx - HB) * 256 + tid;        // < 64*2*128*64 = 1048576
        int wp = j & 63;                       // float4 column (row = 64 float4)
        int h  = (j >> 6) & 127;
        int d  = (j >> 13) & 1;
        int c  = j >> 14;
        int zl = d ? 5 : 1;
        const v4f* S4 = (const v4f*)S;
        long base = ((long)(c * 8 + zl) * 256 + 2 * h) * 64 + wp;
        // student is read exactly once -> nontemporal to keep L2 for pooled
        v4f a = __builtin_nontemporal_load(&S4[base]);
        v4f b = __builtin_nontemporal_load(&S4[base + 64]);
        v4f e = __builtin_nontemporal_load(&S4[base + 16384]);   // next z plane
        v4f f = __builtin_nontemporal_load(&S4[base + 16384 + 64]);
        v2f r;
        r.x = (((a.x + a.y) + (b.x + b.y)) + ((e.x + e.y) + (f.x + f.y))) * 0.125f;
        r.y = (((a.z + a.w) + (b.z + b.w)) + ((e.z + e.w) + (f.z + f.w))) * 0.125f;
        ((v2f*)P)[j] = r;
    }
}

// out[o,s] = |dot(W[o,:], P[:,s]) + B[o] - T[o,s]| * hmv[s] * 10/(sum+1e-4)
//
// W-TILE IN LDS (the R6 failure: wave-uniform W reads through a pointer
// compile to ~1024 serialized s_load+lgkmcnt — scalar-pipe latency bound).
// R7 change: inner loop reads W via ds_read_b128 broadcast (c-step 4): one
// 16B conflict-free broadcast now feeds 8 FMAs (was ds_read_b64 feeding 4),
// halving DS-pipe instruction count — the largest modeled pipe in this
// kernel (~6.8us chip-wide at b64). Accumulation order over c unchanged
// (0..63 sequential fmaf chain) -> bit-identical result.
// o-group 8, grid 64x16=1024 blocks -> 4 waves/SIMD. gridDim.x=64 === 0 mod 8
// keeps all 16 o-groups of a spatial column-chunk on one XCD -> P stays
// L2-resident (~1.05MB/XCD working set).
__global__ __launch_bounds__(256, 4)
void k_final(const float* __restrict__ P, const float* __restrict__ T,
             const float* __restrict__ W, const float* __restrict__ Bb,
             const float* __restrict__ hmv, const float* __restrict__ partial,
             float* __restrict__ out) {
    __shared__ float s_scale;
    __shared__ __align__(16) float sW[8 * 64];   // W o-tile, row-major [oo][c], 2 KB
    int tid = threadIdx.x;
    int o0 = blockIdx.y * 8;

    // stage W tile: 512 floats by 256 threads
    sW[tid]       = W[o0 * 64 + tid];
    sW[tid + 256] = W[o0 * 64 + tid + 256];

    if (tid < 64) {
        float v = partial[tid] + partial[tid + 64];
        for (int off = 32; off > 0; off >>= 1) v += __shfl_down(v, off, 64);
        if (tid == 0) s_scale = 10.0f / (v + 1e-4f);
    }
    __syncthreads();

    int sp = blockIdx.x * 256 + tid;       // float2 index into the s dimension

    v2f acc[8];
#pragma unroll
    for (int oo = 0; oo < 8; ++oo) {
        float b = Bb[o0 + oo];
        acc[oo].x = b; acc[oo].y = b;
    }

    const v2f* Pp = (const v2f*)P + sp;
    const v4f* W4 = (const v4f*)sW;        // [oo][c4], 16 v4f per row
#pragma unroll 4
    for (int c4 = 0; c4 < 16; ++c4) {
        v2f pc0 = Pp[(long)(4 * c4 + 0) * (NSP / 2)];
        v2f pc1 = Pp[(long)(4 * c4 + 1) * (NSP / 2)];
        v2f pc2 = Pp[(long)(4 * c4 + 2) * (NSP / 2)];
        v2f pc3 = Pp[(long)(4 * c4 + 3) * (NSP / 2)];
#pragma unroll
        for (int oo = 0; oo < 8; ++oo) {
            v4f w = W4[oo * 16 + c4];      // LDS broadcast, ds_read_b128
            acc[oo].x = fmaf(w.x, pc0.x, acc[oo].x);
            acc[oo].y = fmaf(w.x, pc0.y, acc[oo].y);
            acc[oo].x = fmaf(w.y, pc1.x, acc[oo].x);
            acc[oo].y = fmaf(w.y, pc1.y, acc[oo].y);
            acc[oo].x = fmaf(w.z, pc2.x, acc[oo].x);
            acc[oo].y = fmaf(w.z, pc2.y, acc[oo].y);
            acc[oo].x = fmaf(w.w, pc3.x, acc[oo].x);
            acc[oo].y = fmaf(w.w, pc3.y, acc[oo].y);
        }
    }

    v2f hm2 = ((const v2f*)hmv)[sp];
    float hwx = hm2.x * s_scale, hwy = hm2.y * s_scale;
    const v2f* T2 = (const v2f*)T;
    v2f* O2 = (v2f*)out;
#pragma unroll
    for (int oo = 0; oo < 8; ++oo) {
        long idx = (long)(o0 + oo) * (NSP / 2) + sp;
        v2f tv = __builtin_nontemporal_load(&T2[idx]);   // teacher read-once
        v2f r;
        r.x = fabsf(acc[oo].x - tv.x) * hwx;
        r.y = fabsf(acc[oo].y - tv.y) * hwy;
        __builtin_nontemporal_store(r, &O2[idx]);        // out write-once
    }
}

// Fallback (ws too small for pooled buffer): pool inline; W-tile in LDS too.
__global__ __launch_bounds__(256, 2)
void k_final_fused(const float* __restrict__ S, const float* __restrict__ T,
                   const float* __restrict__ W, const float* __restrict__ Bb,
                   const float* __restrict__ hmv, const float* __restrict__ partial,
                   float* __restrict__ out) {
    __shared__ float s_scale;
    __shared__ float sW[16 * 64];
    int tid = threadIdx.x;
    int o0 = blockIdx.y * 16;
#pragma unroll
    for (int k = 0; k < 4; ++k) sW[tid + k * 256] = W[o0 * 64 + tid + k * 256];
    if (tid < 64) {
        float v = partial[tid] + partial[tid + 64];
        for (int off = 32; off > 0; off >>= 1) v += __shfl_down(v, off, 64);
        if (tid == 0) s_scale = 10.0f / (v + 1e-4f);
    }
    __syncthreads();
    int s = blockIdx.x * 256 + tid;
    int w = s & 127, h = (s >> 7) & 127, d = s >> 14;
    int zl = d ? 5 : 1;
    const v2f* S2 = (const v2f*)S;
    float acc[16];
#pragma unroll
    for (int oo = 0; oo < 16; ++oo) acc[oo] = Bb[o0 + oo];
#pragma unroll 4
    for (int c = 0; c < 64; ++c) {
        long base = ((long)(c * 8 + zl) * 256 + 2 * h) * 128 + w;
        v2f a = S2[base];
        v2f b = S2[base + 128];
        v2f e = S2[base + 32768];
        v2f f = S2[base + 32768 + 128];
        float pc = (((a.x + a.y) + (b.x + b.y)) + ((e.x + e.y) + (f.x + f.y))) * 0.125f;
#pragma unroll
        for (int oo = 0; oo < 16; ++oo)
            acc[oo] = fmaf(sW[oo * 64 + c], pc, acc[oo]);
    }
    float hmw = hmv[s] * s_scale;
#pragma unroll
    for (int oo = 0; oo < 16; ++oo) {
        int o = o0 + oo;
        out[(long)o * NSP + s] = fabsf(acc[oo] - T[(long)o * NSP + s]) * hmw;
    }
}

extern "C" void kernel_launch(void* const* d_in, const int* in_sizes, int n_in,
                              void* d_out, int out_size, void* d_ws, size_t ws_size,
                              hipStream_t stream) {
    const float* boxes   = (const float*)d_in[0];
    // d_in[1] = gt_labels_3d (unused by the reference output)
    const float* teacher = (const float*)d_in[2];
    const float* student = (const float*)d_in[3];
    const float* conv_w  = (const float*)d_in[4];
    const float* conv_b  = (const float*)d_in[5];
    float* out = (float*)d_out;

    int N = in_sizes[0] / 9;
    if (N > 128) N = 128;

    float* wsF     = (float*)d_ws;
    float* partial = wsF;
    float* hmv     = wsF + 1024;
    float* pooled  = wsF + 65536;

    const size_t need = (size_t)(65536 + 64 * NSP) * sizeof(float);
    if (ws_size >= need) {
        k_stage1<<<HB + PB, 256, 0, stream>>>(boxes, N, student, pooled, hmv, partial);
        k_final<<<dim3(NSP / 512, 16), 256, 0, stream>>>(pooled, teacher, conv_w, conv_b,
                                                         hmv, partial, out);
    } else {
        k_stage1<<<HB, 256, 0, stream>>>(boxes, N, student, /*P unused*/ hmv, hmv, partial);
        k_final_fused<<<dim3(NSP / 256, 8), 256, 0, stream>>>(student, teacher, conv_w, conv_b,
                                                              hmv, partial, out);
    }
}